// Round 10
// baseline (2896.020 us; speedup 1.0000x reference)
//
#include <hip/hip_runtime.h>
#include <hip/hip_bf16.h>
#include <cstdint>
#include <cstddef>

#define T_TOK 4096
#define DMODEL 2048
#define DFF 8192
#define NEXP 8
#define NPAIR (T_TOK * 2)

typedef __bf16 bf16_t;
typedef __bf16 bf16x8 __attribute__((ext_vector_type(8)));
typedef float fx4 __attribute__((ext_vector_type(4)));

__device__ __forceinline__ void gload16(const bf16_t* src, bf16_t* dst) {
    __builtin_amdgcn_global_load_lds(
        (const __attribute__((address_space(1))) uint32_t*)(src),
        (__attribute__((address_space(3))) uint32_t*)(dst), 16, 0, 0);
}

__device__ __forceinline__ bf16x8 pack8(const fx4 lo, const fx4 hi) {
    bf16x8 o;
    o[0] = (bf16_t)lo[0]; o[1] = (bf16_t)lo[1]; o[2] = (bf16_t)lo[2]; o[3] = (bf16_t)lo[3];
    o[4] = (bf16_t)hi[0]; o[5] = (bf16_t)hi[1]; o[6] = (bf16_t)hi[2]; o[7] = (bf16_t)hi[3];
    return o;
}

// ---------------- router ----------------
__global__ void router_kernel(const float* __restrict__ gating, int* __restrict__ counts,
                              int* __restrict__ tok_list, float* __restrict__ w_list) {
    int t = blockIdx.x * blockDim.x + threadIdx.x;
    if (t >= T_TOK) return;
    float l[NEXP];
    float mx = -1e30f;
#pragma unroll
    for (int e = 0; e < NEXP; e++) { l[e] = gating[t * NEXP + e]; mx = fmaxf(mx, l[e]); }
#pragma unroll
    for (int e = 0; e < NEXP; e++) { l[e] = __expf(l[e] - mx); }
    int e0 = 0; float p0 = l[0];
#pragma unroll
    for (int e = 1; e < NEXP; e++) { if (l[e] > p0) { p0 = l[e]; e0 = e; } }
    int e1 = -1; float p1 = -1.0f;
#pragma unroll
    for (int e = 0; e < NEXP; e++) { if (e != e0 && l[e] > p1) { p1 = l[e]; e1 = e; } }
    float inv = 1.0f / (p0 + p1);
    int s0 = atomicAdd(&counts[e0], 1);
    tok_list[e0 * T_TOK + s0] = t; w_list[e0 * T_TOK + s0] = p0 * inv;
    int s1 = atomicAdd(&counts[e1], 1);
    tok_list[e1 * T_TOK + s1] = t; w_list[e1 * T_TOK + s1] = p1 * inv;
}

__global__ void scan_kernel(const int* __restrict__ counts, int* __restrict__ offsets) {
    if (threadIdx.x == 0 && blockIdx.x == 0) {
        int acc = 0;
        for (int e = 0; e < NEXP; e++) { offsets[e] = acc; acc += counts[e]; }
        offsets[NEXP] = acc;
    }
}

// ---------------- fp32 -> bf16 converters ----------------
__global__ void cvt_x_kernel(const float* __restrict__ x, bf16_t* __restrict__ xb) {
    int i = blockIdx.x * blockDim.x + threadIdx.x;
    const fx4* src = (const fx4*)x;
    fx4 v0 = src[2 * i], v1 = src[2 * i + 1];
    *(bf16x8*)(xb + (size_t)i * 8) = pack8(v0, v1);
}

// grid-stride weight converter (8 floats / thread / iter)
__global__ void wcvt_kernel(const float* __restrict__ src, bf16_t* __restrict__ dst, int nchunk) {
    int stride = gridDim.x * blockDim.x;
    for (int i = blockIdx.x * blockDim.x + threadIdx.x; i < nchunk; i += stride) {
        const fx4* s = (const fx4*)src + 2 * (size_t)i;
        fx4 v0 = s[0], v1 = s[1];
        *(bf16x8*)(dst + (size_t)i * 8) = pack8(v0, v1);
    }
}

// ================= bf16-weight gate_up GEMM (m97 structure) =================
// 256 thr = 4 waves (2M x 2C). tile: M=128 tok x 64 h-cols (W: 64g+64u = 128 rows), BK=64, NT=32.
// wave: 64M x 32h dual acc (accg[4][2]+accu[4][2]). BOTH operands via global_load_lds w=16
// (pre-swizzled source, XOR read). Plain 2-barrier loop; 32 KB LDS -> ~4 blocks/CU TLP.
// dispatch: idx=(g2<<8)|(m<<3)|q : q=XCD, m=mslot(32), g2=(e<<4)|ygrp, panel y=q+8*ygrp.
__global__ __launch_bounds__(256, 4) void gateup_kernel(
    const bf16_t* __restrict__ xb, const bf16_t* __restrict__ wg,
    const int* __restrict__ counts, const int* __restrict__ offsets,
    const int* __restrict__ tok_list, bf16_t* __restrict__ h_buf)
{
    const int idx = blockIdx.x;
    const int q = idx & 7;
    const int mslot = (idx >> 3) & 31;
    const int g2 = idx >> 8;             // 0..127
    const int e = g2 >> 4;
    const int cnt = counts[e];
    const int mbase = mslot * 128;
    if (mbase >= cnt) return;
    const int y = q + 8 * (g2 & 15);     // panel 0..127
    const int nb = y * 64;
    const int off_e = offsets[e];

    __shared__ __align__(16) bf16_t lds_a[128 * 64];   // 16 KB
    __shared__ __align__(16) bf16_t lds_w[128 * 64];   // 16 KB (rows 0-63 g, 64-127 u)

    const int tid = threadIdx.x;
    const int lane = tid & 63;
    const int w = tid >> 6;
    const int wm = (w >> 1) * 64;
    const int wc = (w & 1);
    const int l15 = lane & 15;
    const int l4 = lane >> 4;

    // A staging: 4 gload16 per wave, 8 rows per instr, pre-swizzled source chunks
    const bf16_t* a_src[4];
    int a_doff[4];
#pragma unroll
    for (int j = 0; j < 4; j++) {
        int row = (w * 4 + j) * 8 + (lane >> 3);
        int c8 = (lane & 7) ^ (row & 7);
        int slot = mbase + row;
        int tok = tok_list[e * T_TOK + (slot < cnt ? slot : cnt - 1)];
        a_src[j] = xb + (size_t)tok * DMODEL + c8 * 8;
        a_doff[j] = (w * 4 + j) * 512;
    }
    // W staging (bf16): 4 gload16 per wave, same 8-row pattern over 128 W-rows
    const bf16_t* w_src[4];
    int w_doff[4];
    const bf16_t* wg_e = wg + (size_t)e * (2 * DFF) * DMODEL;
#pragma unroll
    for (int j = 0; j < 4; j++) {
        int row = (w * 4 + j) * 8 + (lane >> 3);       // 0..127
        int c8 = (lane & 7) ^ (row & 7);
        int grow = (row < 64) ? (nb + row) : (DFF + nb + (row - 64));
        w_src[j] = wg_e + (size_t)grow * DMODEL + c8 * 8;
        w_doff[j] = (w * 4 + j) * 512;
    }

    fx4 accg[4][2] = {};
    fx4 accu[4][2] = {};

    for (int k0 = 0; k0 < DMODEL; k0 += 64) {
#pragma unroll
        for (int j = 0; j < 4; j++) {
            gload16(a_src[j] + k0, &lds_a[a_doff[j]]);
            gload16(w_src[j] + k0, &lds_w[w_doff[j]]);
        }
        __syncthreads();
#pragma unroll
        for (int kp = 0; kp < 2; kp++) {
            const int ke = kp * 4 + l4;
            bf16x8 af[4], gf[2], uf[2];
#pragma unroll
            for (int m = 0; m < 4; m++) {
                int r = wm + m * 16 + l15;
                af[m] = *(const bf16x8*)(&lds_a[r * 64 + ((ke ^ (r & 7)) * 8)]);
            }
#pragma unroll
            for (int n = 0; n < 2; n++) {
                int r = wc * 32 + n * 16 + l15;
                gf[n] = *(const bf16x8*)(&lds_w[r * 64 + ((ke ^ (r & 7)) * 8)]);
                uf[n] = *(const bf16x8*)(&lds_w[(r + 64) * 64 + (((ke) ^ ((r + 64) & 7)) * 8)]);
            }
#pragma unroll
            for (int m = 0; m < 4; m++)
#pragma unroll
                for (int n = 0; n < 2; n++) {
                    accg[m][n] = __builtin_amdgcn_mfma_f32_16x16x32_bf16(af[m], gf[n], accg[m][n], 0, 0, 0);
                    accu[m][n] = __builtin_amdgcn_mfma_f32_16x16x32_bf16(af[m], uf[n], accu[m][n], 0, 0, 0);
                }
        }
        __syncthreads();
    }

    const int colbase = nb + wc * 32 + l15;
#pragma unroll
    for (int m = 0; m < 4; m++) {
        int rb = wm + m * 16 + l4 * 4;
#pragma unroll
        for (int j = 0; j < 4; j++) {
            int slot = mbase + rb + j;
            if (slot < cnt) {
                size_t hrow = (size_t)(off_e + slot);
#pragma unroll
                for (int n = 0; n < 2; n++) {
                    float g = accg[m][n][j];
                    float u = accu[m][n][j];
                    float hv = g * u / (1.0f + __expf(-g));
                    h_buf[hrow * DFF + colbase + n * 16] = (bf16_t)hv;
                }
            }
        }
    }
}

// ================= bf16-weight down GEMM (m97 structure) =================
// 256 thr = 4 waves (2M x 2N). tile: M=128 pairs x 128 out-cols, BK=64, NT=128. wave 64x64 acc[4][4].
// dispatch: idx=(e<<9)|(pp<<8)|(m<<3)|q : panel y=q+8*pp, m=mslot(32)
__global__ __launch_bounds__(256, 4) void down_kernel(
    const bf16_t* __restrict__ h_buf, const bf16_t* __restrict__ wd,
    const int* __restrict__ counts, const int* __restrict__ offsets,
    const int* __restrict__ tok_list, const float* __restrict__ w_list,
    float* __restrict__ out)
{
    const int idx = blockIdx.x;
    const int q = idx & 7;
    const int mslot = (idx >> 3) & 31;
    const int rest = idx >> 8;
    const int pp = rest & 1;
    const int e = rest >> 1;
    const int cnt = counts[e];
    const int mbase = mslot * 128;
    if (mbase >= cnt) return;
    const int y = q + 8 * pp;
    const int nbase = y * 128;
    const int off_e = offsets[e];

    __shared__ __align__(16) bf16_t lds_a[128 * 64];
    __shared__ __align__(16) bf16_t lds_w[128 * 64];

    const int tid = threadIdx.x;
    const int lane = tid & 63;
    const int w = tid >> 6;
    const int wm = (w >> 1) * 64;
    const int wn = (w & 1) * 64;
    const int l15 = lane & 15;
    const int l4 = lane >> 4;

    const bf16_t* a_src[4];
    int a_doff[4];
#pragma unroll
    for (int j = 0; j < 4; j++) {
        int row = (w * 4 + j) * 8 + (lane >> 3);
        int c8 = (lane & 7) ^ (row & 7);
        int slot = mbase + row;
        int hrow = off_e + (slot < cnt ? slot : cnt - 1);
        a_src[j] = h_buf + (size_t)hrow * DFF + c8 * 8;
        a_doff[j] = (w * 4 + j) * 512;
    }
    const bf16_t* w_src[4];
    int w_doff[4];
    const bf16_t* wd_e = wd + (size_t)e * DMODEL * DFF;
#pragma unroll
    for (int j = 0; j < 4; j++) {
        int row = (w * 4 + j) * 8 + (lane >> 3);
        int c8 = (lane & 7) ^ (row & 7);
        w_src[j] = wd_e + (size_t)(nbase + row) * DFF + c8 * 8;
        w_doff[j] = (w * 4 + j) * 512;
    }

    fx4 acc[4][4] = {};

    for (int k0 = 0; k0 < DFF; k0 += 64) {
#pragma unroll
        for (int j = 0; j < 4; j++) {
            gload16(a_src[j] + k0, &lds_a[a_doff[j]]);
            gload16(w_src[j] + k0, &lds_w[w_doff[j]]);
        }
        __syncthreads();
#pragma unroll
        for (int kp = 0; kp < 2; kp++) {
            const int ke = kp * 4 + l4;
            bf16x8 af[4], bfr[4];
#pragma unroll
            for (int m = 0; m < 4; m++) {
                int r = wm + m * 16 + l15;
                af[m] = *(const bf16x8*)(&lds_a[r * 64 + ((ke ^ (r & 7)) * 8)]);
            }
#pragma unroll
            for (int n = 0; n < 4; n++) {
                int r = wn + n * 16 + l15;
                bfr[n] = *(const bf16x8*)(&lds_w[r * 64 + ((ke ^ (r & 7)) * 8)]);
            }
#pragma unroll
            for (int m = 0; m < 4; m++)
#pragma unroll
                for (int n = 0; n < 4; n++)
                    acc[m][n] = __builtin_amdgcn_mfma_f32_16x16x32_bf16(af[m], bfr[n], acc[m][n], 0, 0, 0);
        }
        __syncthreads();
    }

    const int colb = nbase + wn + l15;
#pragma unroll
    for (int m = 0; m < 4; m++) {
        int rb = wm + m * 16 + l4 * 4;
#pragma unroll
        for (int j = 0; j < 4; j++) {
            int slot = mbase + rb + j;
            if (slot < cnt) {
                int tok = tok_list[e * T_TOK + slot];
                float wgt = w_list[e * T_TOK + slot];
#pragma unroll
                for (int n = 0; n < 4; n++)
                    atomicAdd(&out[(size_t)tok * DMODEL + colb + n * 16], wgt * acc[m][n][j]);
            }
        }
    }
}

// ================= FALLBACK (ws too small): R5 proven fp32-weight kernels =================
__global__ __launch_bounds__(512, 4) void gateup_f32_kernel(
    const bf16_t* __restrict__ xb, const float* __restrict__ gup,
    const int* __restrict__ counts, const int* __restrict__ offsets,
    const int* __restrict__ tok_list, bf16_t* __restrict__ h_buf)
{
    const int idx = blockIdx.x;
    const int q = idx & 7;
    const int mslot = (idx >> 3) & 15;
    const int g2 = idx >> 7;
    const int e = g2 >> 4;
    const int cnt = counts[e];
    const int mbase = mslot * 256;
    if (mbase >= cnt) return;
    const int y = q + 8 * (g2 & 15);
    const int nb = y * 64;
    const int off_e = offsets[e];

    __shared__ __align__(16) bf16_t lds_a[256 * 64];
    __shared__ __align__(16) bf16_t lds_w[128 * 64];

    const int tid = threadIdx.x;
    const int lane = tid & 63;
    const int w = tid >> 6;
    const int wm = (w >> 1) * 64;
    const int wc = (w & 1);

    const bf16_t* a_src[4];
    int a_doff[4];
#pragma unroll
    for (int j = 0; j < 4; j++) {
        int row = (w * 4 + j) * 8 + (lane >> 3);
        int cs = (lane & 7) ^ (row & 7);
        int slot = mbase + row;
        int tok = tok_list[e * T_TOK + (slot < cnt ? slot : cnt - 1)];
        a_src[j] = xb + (size_t)tok * DMODEL + cs * 8;
        a_doff[j] = (w * 4 + j) * 512;
    }
    const float* w_src[2];
    int w_st[2];
    const float* gup_e = gup + (size_t)e * (2 * DFF) * DMODEL;
#pragma unroll
    for (int t = 0; t < 2; t++) {
        int cid = t * 512 + tid;
        int row = cid >> 3, c = cid & 7;
        int grow = (row < 64) ? (nb + row) : (DFF + nb + (row - 64));
        w_src[t] = gup_e + (size_t)grow * DMODEL + c * 8;
        w_st[t] = row * 64 + ((c ^ (row & 7)) * 8);
    }

    fx4 accg[4][2] = {};
    fx4 accu[4][2] = {};

    for (int k0 = 0; k0 < DMODEL; k0 += 64) {
#pragma unroll
        for (int j = 0; j < 4; j++) gload16(a_src[j] + k0, &lds_a[a_doff[j]]);
#pragma unroll
        for (int t = 0; t < 2; t++) {
            fx4 lo = *(const fx4*)(w_src[t] + k0);
            fx4 hi = *(const fx4*)(w_src[t] + k0 + 4);
            *(bf16x8*)(&lds_w[w_st[t]]) = pack8(lo, hi);
        }
        __syncthreads();
#pragma unroll
        for (int kp = 0; kp < 2; kp++) {
            const int ke = kp * 4 + (lane >> 4);
            bf16x8 af[4], gf[2], uf[2];
#pragma unroll
            for (int m = 0; m < 4; m++) {
                int r = wm + m * 16 + (lane & 15);
                af[m] = *(const bf16x8*)(&lds_a[r * 64 + ((ke ^ (r & 7)) * 8)]);
            }
#pragma unroll
            for (int n = 0; n < 2; n++) {
                int r = wc * 32 + n * 16 + (lane & 15);
                gf[n] = *(const bf16x8*)(&lds_w[r * 64 + ((ke ^ (r & 7)) * 8)]);
                uf[n] = *(const bf16x8*)(&lds_w[(r + 64) * 64 + ((ke ^ (r & 7)) * 8)]);
            }
#pragma unroll
            for (int m = 0; m < 4; m++)
#pragma unroll
                for (int n = 0; n < 2; n++) {
                    accg[m][n] = __builtin_amdgcn_mfma_f32_16x16x32_bf16(af[m], gf[n], accg[m][n], 0, 0, 0);
                    accu[m][n] = __builtin_amdgcn_mfma_f32_16x16x32_bf16(af[m], uf[n], accu[m][n], 0, 0, 0);
                }
        }
        __syncthreads();
    }

    const int colbase = nb + wc * 32 + (lane & 15);
#pragma unroll
    for (int m = 0; m < 4; m++) {
        int rb = wm + m * 16 + ((lane >> 4) * 4);
#pragma unroll
        for (int j = 0; j < 4; j++) {
            int slot = mbase + rb + j;
            if (slot < cnt) {
                size_t hrow = (size_t)(off_e + slot);
#pragma unroll
                for (int n = 0; n < 2; n++) {
                    float g = accg[m][n][j];
                    float u = accu[m][n][j];
                    float hv = g * u / (1.0f + __expf(-g));
                    h_buf[hrow * DFF + colbase + n * 16] = (bf16_t)hv;
                }
            }
        }
    }
}

__global__ __launch_bounds__(512, 4) void down_f32_kernel(
    const bf16_t* __restrict__ h_buf, const float* __restrict__ dwn,
    const int* __restrict__ counts, const int* __restrict__ offsets,
    const int* __restrict__ tok_list, const float* __restrict__ w_list,
    float* __restrict__ out)
{
    const int idx = blockIdx.x;
    const int q = idx & 7;
    const int mslot = (idx >> 3) & 15;
    const int rest = idx >> 7;
    const int pp = rest & 1;
    const int e = rest >> 1;
    const int cnt = counts[e];
    const int mbase = mslot * 256;
    if (mbase >= cnt) return;
    const int y = q + 8 * pp;
    const int nbase = y * 128;
    const int off_e = offsets[e];

    __shared__ __align__(16) bf16_t lds_a[256 * 64];
    __shared__ __align__(16) bf16_t lds_w[128 * 64];

    const int tid = threadIdx.x;
    const int lane = tid & 63;
    const int w = tid >> 6;
    const int wm = (w >> 1) * 64;
    const int wn = (w & 1) * 64;

    const bf16_t* a_src[4];
    int a_doff[4];
#pragma unroll
    for (int j = 0; j < 4; j++) {
        int row = (w * 4 + j) * 8 + (lane >> 3);
        int cs = (lane & 7) ^ (row & 7);
        int slot = mbase + row;
        int hrow = off_e + (slot < cnt ? slot : cnt - 1);
        a_src[j] = h_buf + (size_t)hrow * DFF + cs * 8;
        a_doff[j] = (w * 4 + j) * 512;
    }
    const float* w_src[2];
    int w_st[2];
    const float* dwn_e = dwn + (size_t)e * DMODEL * DFF;
#pragma unroll
    for (int t = 0; t < 2; t++) {
        int cid = t * 512 + tid;
        int row = cid >> 3, c = cid & 7;
        w_src[t] = dwn_e + (size_t)(nbase + row) * DFF + c * 8;
        w_st[t] = row * 64 + ((c ^ (row & 7)) * 8);
    }

    fx4 acc[4][4] = {};

    for (int k0 = 0; k0 < DFF; k0 += 64) {
#pragma unroll
        for (int j = 0; j < 4; j++) gload16(a_src[j] + k0, &lds_a[a_doff[j]]);
#pragma unroll
        for (int t = 0; t < 2; t++) {
            fx4 lo = *(const fx4*)(w_src[t] + k0);
            fx4 hi = *(const fx4*)(w_src[t] + k0 + 4);
            *(bf16x8*)(&lds_w[w_st[t]]) = pack8(lo, hi);
        }
        __syncthreads();
#pragma unroll
        for (int kp = 0; kp < 2; kp++) {
            const int ke = kp * 4 + (lane >> 4);
            bf16x8 af[4], bfr[4];
#pragma unroll
            for (int m = 0; m < 4; m++) {
                int r = wm + m * 16 + (lane & 15);
                af[m] = *(const bf16x8*)(&lds_a[r * 64 + ((ke ^ (r & 7)) * 8)]);
            }
#pragma unroll
            for (int n = 0; n < 4; n++) {
                int r = wn + n * 16 + (lane & 15);
                bfr[n] = *(const bf16x8*)(&lds_w[r * 64 + ((ke ^ (r & 7)) * 8)]);
            }
#pragma unroll
            for (int m = 0; m < 4; m++)
#pragma unroll
                for (int n = 0; n < 4; n++)
                    acc[m][n] = __builtin_amdgcn_mfma_f32_16x16x32_bf16(af[m], bfr[n], acc[m][n], 0, 0, 0);
        }
        __syncthreads();
    }

    const int colb = nbase + wn + (lane & 15);
#pragma unroll
    for (int m = 0; m < 4; m++) {
        int rb = wm + m * 16 + ((lane >> 4) * 4);
#pragma unroll
        for (int j = 0; j < 4; j++) {
            int slot = mbase + rb + j;
            if (slot < cnt) {
                int tok = tok_list[e * T_TOK + slot];
                float wgt = w_list[e * T_TOK + slot];
#pragma unroll
                for (int n = 0; n < 4; n++)
                    atomicAdd(&out[(size_t)tok * DMODEL + colb + n * 16], wgt * acc[m][n][j]);
            }
        }
    }
}

// ---------------- launch ----------------
extern "C" void kernel_launch(void* const* d_in, const int* in_sizes, int n_in,
                              void* d_out, int out_size, void* d_ws, size_t ws_size,
                              hipStream_t stream) {
    const float* x      = (const float*)d_in[0];
    const float* gating = (const float*)d_in[1];
    const float* gup    = (const float*)d_in[2];
    const float* dwn    = (const float*)d_in[3];
    float* out = (float*)d_out;

    char* ws = (char*)d_ws;
    int*    counts   = (int*)(ws + 0);
    int*    offsets  = (int*)(ws + 64);
    int*    tok_list = (int*)(ws + 128);
    float*  w_list   = (float*)(ws + 128 + 131072);
    bf16_t* xb       = (bf16_t*)(ws + 262400);
    bf16_t* h_buf    = (bf16_t*)(ws + 17039872);          // 134,217,728 B -> ends 151,257,600
    bf16_t* wg_b     = (bf16_t*)(ws + 151257600);         // 536,870,912 B -> ends 688,128,512
    bf16_t* wd_b     = (bf16_t*)(ws + 688128512);         // 268,435,456 B -> ends 956,563,968
    const size_t WS_NEED = 956563968ull;

    hipMemsetAsync(counts, 0, 64, stream);
    hipMemsetAsync(out, 0, (size_t)out_size * sizeof(float), stream);

    router_kernel<<<dim3(T_TOK / 256), dim3(256), 0, stream>>>(gating, counts, tok_list, w_list);
    scan_kernel<<<dim3(1), dim3(64), 0, stream>>>(counts, offsets);
    cvt_x_kernel<<<dim3(T_TOK * DMODEL / 8 / 256), dim3(256), 0, stream>>>(x, xb);

    if (ws_size >= WS_NEED) {
        // pre-convert weights to bf16 (memory-bound, ~330 us total)
        wcvt_kernel<<<dim3(2048), dim3(256), 0, stream>>>(gup, wg_b, NEXP * 2 * DFF * DMODEL / 8);
        wcvt_kernel<<<dim3(2048), dim3(256), 0, stream>>>(dwn, wd_b, NEXP * DMODEL * DFF / 8);

        // 128 g2 * 32 m-slots * 8 XCD = 32768 blocks
        gateup_kernel<<<dim3(32768), dim3(256), 0, stream>>>(
            xb, wg_b, counts, offsets, tok_list, h_buf);
        // 8 e * 2 pp * 32 m-slots * 8 XCD = 4096 blocks
        down_kernel<<<dim3(4096), dim3(256), 0, stream>>>(
            h_buf, wd_b, counts, offsets, tok_list, w_list, out);
    } else {
        gateup_f32_kernel<<<dim3(16384), dim3(512), 0, stream>>>(
            xb, gup, counts, offsets, tok_list, h_buf);
        down_f32_kernel<<<dim3(2048), dim3(512), 0, stream>>>(
            h_buf, dwn, counts, offsets, tok_list, w_list, out);
    }
}

// Round 11
// 1754.679 us; speedup vs baseline: 1.6505x; 1.6505x over previous
//
#include <hip/hip_runtime.h>
#include <hip/hip_bf16.h>
#include <cstdint>
#include <cstddef>

#define T_TOK 4096
#define DMODEL 2048
#define DFF 8192
#define NEXP 8
#define NPAIR (T_TOK * 2)

typedef __bf16 bf16_t;
typedef __bf16 bf16x8 __attribute__((ext_vector_type(8)));
typedef float fx4 __attribute__((ext_vector_type(4)));

__device__ __forceinline__ void gload16(const bf16_t* src, bf16_t* dst) {
    __builtin_amdgcn_global_load_lds(
        (const __attribute__((address_space(1))) uint32_t*)(src),
        (__attribute__((address_space(3))) uint32_t*)(dst), 16, 0, 0);
}

__device__ __forceinline__ bf16x8 pack8(const fx4 lo, const fx4 hi) {
    bf16x8 o;
    o[0] = (bf16_t)lo[0]; o[1] = (bf16_t)lo[1]; o[2] = (bf16_t)lo[2]; o[3] = (bf16_t)lo[3];
    o[4] = (bf16_t)hi[0]; o[5] = (bf16_t)hi[1]; o[6] = (bf16_t)hi[2]; o[7] = (bf16_t)hi[3];
    return o;
}

// ---------------- router ----------------
__global__ void router_kernel(const float* __restrict__ gating, int* __restrict__ counts,
                              int* __restrict__ tok_list, float* __restrict__ w_list) {
    int t = blockIdx.x * blockDim.x + threadIdx.x;
    if (t >= T_TOK) return;
    float l[NEXP];
    float mx = -1e30f;
#pragma unroll
    for (int e = 0; e < NEXP; e++) { l[e] = gating[t * NEXP + e]; mx = fmaxf(mx, l[e]); }
#pragma unroll
    for (int e = 0; e < NEXP; e++) { l[e] = __expf(l[e] - mx); }
    int e0 = 0; float p0 = l[0];
#pragma unroll
    for (int e = 1; e < NEXP; e++) { if (l[e] > p0) { p0 = l[e]; e0 = e; } }
    int e1 = -1; float p1 = -1.0f;
#pragma unroll
    for (int e = 0; e < NEXP; e++) { if (e != e0 && l[e] > p1) { p1 = l[e]; e1 = e; } }
    float inv = 1.0f / (p0 + p1);
    int s0 = atomicAdd(&counts[e0], 1);
    tok_list[e0 * T_TOK + s0] = t; w_list[e0 * T_TOK + s0] = p0 * inv;
    int s1 = atomicAdd(&counts[e1], 1);
    tok_list[e1 * T_TOK + s1] = t; w_list[e1 * T_TOK + s1] = p1 * inv;
}

__global__ void scan_kernel(const int* __restrict__ counts, int* __restrict__ offsets) {
    if (threadIdx.x == 0 && blockIdx.x == 0) {
        int acc = 0;
        for (int e = 0; e < NEXP; e++) { offsets[e] = acc; acc += counts[e]; }
        offsets[NEXP] = acc;
    }
}

// ---------------- x fp32 -> bf16 ----------------
__global__ void cvt_x_kernel(const float* __restrict__ x, bf16_t* __restrict__ xb) {
    int i = blockIdx.x * blockDim.x + threadIdx.x;
    const fx4* src = (const fx4*)x;
    fx4 v0 = src[2 * i], v1 = src[2 * i + 1];
    *(bf16x8*)(xb + (size_t)i * 8) = pack8(v0, v1);
}

// ================= gate_up GEMM (R5 schedule, doubled N-tile) =================
// 512 thr = 8 waves (4M x 2C). tile: M=256 tok x 128 h-cols (W: 128 g + 128 u = 256 rows), BK=64.
// wave: 64M x 64h dual acc (accg[4][4] + accu[4][4] = 128 acc VGPR).
// A: global_load_lds w=16 (pre-swizzled src). W: fp32 vec-load -> bf16 -> swizzled ds_write.
// Single-buffered plain 2-barrier loop. LDS = A 32K + W 32K = 64 KB -> 2 blocks/CU.
// dispatch: idx=(g2<<7)|(m<<3)|q : q=XCD, m=mslot(16), g2=(e<<3)|ygrp, panel y=q+8*ygrp (64 panels).
__global__ __launch_bounds__(512, 2) void gateup_kernel(
    const bf16_t* __restrict__ xb, const float* __restrict__ gup,
    const int* __restrict__ counts, const int* __restrict__ offsets,
    const int* __restrict__ tok_list, bf16_t* __restrict__ h_buf)
{
    const int idx = blockIdx.x;
    const int q = idx & 7;
    const int mslot = (idx >> 3) & 15;
    const int g2 = idx >> 7;             // 0..63
    const int e = g2 >> 3;
    const int cnt = counts[e];
    const int mbase = mslot * 256;
    if (mbase >= cnt) return;
    const int y = q + 8 * (g2 & 7);      // panel 0..63
    const int nb = y * 128;
    const int off_e = offsets[e];

    __shared__ __align__(16) bf16_t lds_a[256 * 64];   // 32 KB
    __shared__ __align__(16) bf16_t lds_w[256 * 64];   // 32 KB (rows 0-127 g, 128-255 u)

    const int tid = threadIdx.x;
    const int lane = tid & 63;
    const int w = tid >> 6;
    const int wm = (w >> 1) * 64;
    const int wc = (w & 1);
    const int l15 = lane & 15;
    const int l4 = lane >> 4;

    // A staging: 32 gload16 per block (4 per wave), 8 rows per instr, pre-swizzled source
    const bf16_t* a_src[4];
    int a_doff[4];
#pragma unroll
    for (int j = 0; j < 4; j++) {
        int row = (w * 4 + j) * 8 + (lane >> 3);
        int c8 = (lane & 7) ^ (row & 7);
        int slot = mbase + row;
        int tok = tok_list[e * T_TOK + (slot < cnt ? slot : cnt - 1)];
        a_src[j] = xb + (size_t)tok * DMODEL + c8 * 8;
        a_doff[j] = (w * 4 + j) * 512;
    }
    // W staging: 2048 8-float chunks (256 rows x 8), 4 per thread
    const float* w_src[4];
    int w_st[4];
    const float* gup_e = gup + (size_t)e * (2 * DFF) * DMODEL;
#pragma unroll
    for (int c4 = 0; c4 < 4; c4++) {
        int cid = c4 * 512 + tid;
        int row = cid >> 3, c = cid & 7;
        int grow = (row < 128) ? (nb + row) : (DFF + nb + (row - 128));
        w_src[c4] = gup_e + (size_t)grow * DMODEL + c * 8;
        w_st[c4] = row * 64 + ((c ^ (row & 7)) * 8);
    }

    fx4 accg[4][4] = {};
    fx4 accu[4][4] = {};

    for (int k0 = 0; k0 < DMODEL; k0 += 64) {
#pragma unroll
        for (int j = 0; j < 4; j++) gload16(a_src[j] + k0, &lds_a[a_doff[j]]);
#pragma unroll
        for (int c4 = 0; c4 < 4; c4++) {
            fx4 lo = *(const fx4*)(w_src[c4] + k0);
            fx4 hi = *(const fx4*)(w_src[c4] + k0 + 4);
            *(bf16x8*)(&lds_w[w_st[c4]]) = pack8(lo, hi);
        }
        __syncthreads();
#pragma unroll
        for (int kp = 0; kp < 2; kp++) {
            const int ke = kp * 4 + l4;
            bf16x8 af[4], gf[4], uf[4];
#pragma unroll
            for (int m = 0; m < 4; m++) {
                int r = wm + m * 16 + l15;
                af[m] = *(const bf16x8*)(&lds_a[r * 64 + ((ke ^ (r & 7)) * 8)]);
            }
#pragma unroll
            for (int n = 0; n < 4; n++) {
                int r = wc * 64 + n * 16 + l15;
                gf[n] = *(const bf16x8*)(&lds_w[r * 64 + ((ke ^ (r & 7)) * 8)]);
                uf[n] = *(const bf16x8*)(&lds_w[(r + 128) * 64 + ((ke ^ (r & 7)) * 8)]);
            }
#pragma unroll
            for (int m = 0; m < 4; m++)
#pragma unroll
                for (int n = 0; n < 4; n++) {
                    accg[m][n] = __builtin_amdgcn_mfma_f32_16x16x32_bf16(af[m], gf[n], accg[m][n], 0, 0, 0);
                    accu[m][n] = __builtin_amdgcn_mfma_f32_16x16x32_bf16(af[m], uf[n], accu[m][n], 0, 0, 0);
                }
        }
        __syncthreads();
    }

    // epilogue: h = silu(g) * u -> bf16
    const int colbase = nb + wc * 64 + l15;
#pragma unroll
    for (int m = 0; m < 4; m++) {
        int rb = wm + m * 16 + l4 * 4;
#pragma unroll
        for (int j = 0; j < 4; j++) {
            int slot = mbase + rb + j;
            if (slot < cnt) {
                size_t hrow = (size_t)(off_e + slot);
#pragma unroll
                for (int n = 0; n < 4; n++) {
                    float g = accg[m][n][j];
                    float u = accu[m][n][j];
                    float hv = g * u / (1.0f + __expf(-g));
                    h_buf[hrow * DFF + colbase + n * 16] = (bf16_t)hv;
                }
            }
        }
    }
}

// ================= down GEMM (R5 verbatim) =================
// 512 thr = 8 waves (4M x 2N). tile M=256 pairs x 128 out-cols, BK=64, 128 K-steps.
// wave 64x64: acc[4][4]. A via gload_lds, W fp32->bf16 LDS. 2-barrier loop.
// dispatch: idx=(e<<8)|(pp<<7)|(m<<3)|q : panel y=q+8*pp (16 panels of 128 cols)
__global__ __launch_bounds__(512, 4) void down_kernel(
    const bf16_t* __restrict__ h_buf, const float* __restrict__ dwn,
    const int* __restrict__ counts, const int* __restrict__ offsets,
    const int* __restrict__ tok_list, const float* __restrict__ w_list,
    float* __restrict__ out)
{
    const int idx = blockIdx.x;
    const int q = idx & 7;
    const int mslot = (idx >> 3) & 15;
    const int rest = idx >> 7;
    const int pp = rest & 1;
    const int e = rest >> 1;
    const int cnt = counts[e];
    const int mbase = mslot * 256;
    if (mbase >= cnt) return;
    const int y = q + 8 * pp;          // 0..15
    const int nbase = y * 128;
    const int off_e = offsets[e];

    __shared__ __align__(16) bf16_t lds_a[256 * 64];   // 32 KB
    __shared__ __align__(16) bf16_t lds_w[128 * 64];   // 16 KB

    const int tid = threadIdx.x;
    const int lane = tid & 63;
    const int w = tid >> 6;
    const int wm = (w >> 1) * 64;
    const int wn = (w & 1) * 64;

    const bf16_t* a_src[4];
    int a_doff[4];
#pragma unroll
    for (int j = 0; j < 4; j++) {
        int row = (w * 4 + j) * 8 + (lane >> 3);
        int cs = (lane & 7) ^ (row & 7);
        int slot = mbase + row;
        int hrow = off_e + (slot < cnt ? slot : cnt - 1);
        a_src[j] = h_buf + (size_t)hrow * DFF + cs * 8;
        a_doff[j] = (w * 4 + j) * 512;
    }
    const float* w_src[2];
    int w_st[2];
    const float* dwn_e = dwn + (size_t)e * DMODEL * DFF;
#pragma unroll
    for (int t = 0; t < 2; t++) {
        int cid = t * 512 + tid;
        int row = cid >> 3, c = cid & 7;
        w_src[t] = dwn_e + (size_t)(nbase + row) * DFF + c * 8;
        w_st[t] = row * 64 + ((c ^ (row & 7)) * 8);
    }

    fx4 acc[4][4] = {};

    for (int k0 = 0; k0 < DFF; k0 += 64) {
#pragma unroll
        for (int j = 0; j < 4; j++) gload16(a_src[j] + k0, &lds_a[a_doff[j]]);
#pragma unroll
        for (int t = 0; t < 2; t++) {
            fx4 lo = *(const fx4*)(w_src[t] + k0);
            fx4 hi = *(const fx4*)(w_src[t] + k0 + 4);
            *(bf16x8*)(&lds_w[w_st[t]]) = pack8(lo, hi);
        }
        __syncthreads();
#pragma unroll
        for (int kp = 0; kp < 2; kp++) {
            const int ke = kp * 4 + (lane >> 4);
            bf16x8 af[4], bfr[4];
#pragma unroll
            for (int m = 0; m < 4; m++) {
                int r = wm + m * 16 + (lane & 15);
                af[m] = *(const bf16x8*)(&lds_a[r * 64 + ((ke ^ (r & 7)) * 8)]);
            }
#pragma unroll
            for (int n = 0; n < 4; n++) {
                int r = wn + n * 16 + (lane & 15);
                bfr[n] = *(const bf16x8*)(&lds_w[r * 64 + ((ke ^ (r & 7)) * 8)]);
            }
#pragma unroll
            for (int m = 0; m < 4; m++)
#pragma unroll
                for (int n = 0; n < 4; n++)
                    acc[m][n] = __builtin_amdgcn_mfma_f32_16x16x32_bf16(af[m], bfr[n], acc[m][n], 0, 0, 0);
        }
        __syncthreads();
    }

    const int colb = nbase + wn + (lane & 15);
#pragma unroll
    for (int m = 0; m < 4; m++) {
        int rb = wm + m * 16 + ((lane >> 4) * 4);
#pragma unroll
        for (int j = 0; j < 4; j++) {
            int slot = mbase + rb + j;
            if (slot < cnt) {
                int tok = tok_list[e * T_TOK + slot];
                float wgt = w_list[e * T_TOK + slot];
#pragma unroll
                for (int n = 0; n < 4; n++)
                    atomicAdd(&out[(size_t)tok * DMODEL + colb + n * 16], wgt * acc[m][n][j]);
            }
        }
    }
}

// ---------------- launch ----------------
extern "C" void kernel_launch(void* const* d_in, const int* in_sizes, int n_in,
                              void* d_out, int out_size, void* d_ws, size_t ws_size,
                              hipStream_t stream) {
    const float* x      = (const float*)d_in[0];
    const float* gating = (const float*)d_in[1];
    const float* gup    = (const float*)d_in[2];
    const float* dwn    = (const float*)d_in[3];
    float* out = (float*)d_out;

    char* ws = (char*)d_ws;
    int*    counts   = (int*)(ws + 0);
    int*    offsets  = (int*)(ws + 64);
    int*    tok_list = (int*)(ws + 128);
    float*  w_list   = (float*)(ws + 128 + 131072);
    bf16_t* xb       = (bf16_t*)(ws + 262400);
    bf16_t* h_buf    = (bf16_t*)(ws + 17039872);

    hipMemsetAsync(counts, 0, 64, stream);
    hipMemsetAsync(out, 0, (size_t)out_size * sizeof(float), stream);

    router_kernel<<<dim3(T_TOK / 256), dim3(256), 0, stream>>>(gating, counts, tok_list, w_list);
    scan_kernel<<<dim3(1), dim3(64), 0, stream>>>(counts, offsets);
    cvt_x_kernel<<<dim3(T_TOK * DMODEL / 8 / 256), dim3(256), 0, stream>>>(x, xb);

    // 64 g2 (e,ygrp) * 16 m-slots * 8 XCD-slots = 8192 blocks
    gateup_kernel<<<dim3(8192), dim3(512), 0, stream>>>(
        xb, gup, counts, offsets, tok_list, h_buf);

    // 8 e * 2 pp * 16 m-slots * 8 XCD-slots = 2048 blocks
    down_kernel<<<dim3(2048), dim3(512), 0, stream>>>(
        h_buf, dwn, counts, offsets, tok_list, w_list, out);
}